// Round 1
// baseline (1588.624 us; speedup 1.0000x reference)
//
#include <hip/hip_runtime.h>

// Problem constants
#define B_    64
#define T_    512
#define KDIM  1024
#define HID_  1024

// R13 geometry: lane-pair split, 64x128 block tile
#define BM 64     // t-chunk per block iteration (8 chunks)
#define BN 128    // h-tile per block
#define BK 32     // two numpy 16-k blocks per slice
#define LDA 36    // padded LDS row: 32 + 4 floats
#define NSL 256   // total slices = (T_/BM)*(KDIM/BK)
#define SPC 32    // slices per chunk = KDIM/BK
#define BOFF 2304   // Bs offset within a buffer (64*36 floats)
#define BUFSZ 6912  // per-buffer floats: 2304 (A) + 128*36 (B)
#define ISMOFF 6912 // Ism based at AB1 (spans AB1 + 1344-float pad)
#define ISMLD 129
#define BSHOFF 15168 // 2*BUFSZ + 1344
// total smem floats = 15168 + 128 = 15296 (61184 B -> 2 blocks/CU)

// f32 correctly rounded from python float math.exp(-1.0/20.0)
#define ALPHA_F 0.95122942450071400909f

typedef float v2f __attribute__((ext_vector_type(2)));

// Bit-faithful replication of the harness numpy f32 reference: per output
// element 4 f32 accumulator lanes (lane l sums k = l mod 4), 16-k blocks
// ascending, q descending within block, mul/add separately rounded (no FMA),
// hadd tree (l0+l1)+(l2+l3), one f32 bias add; f32 scan. Chain byte-identical
// to R6..R12 (all PASSED).
//
// R13 vs R12 (1.505 ms, VALUBusy 72%): R12 was LDS-return-path bound, not
// VALU bound (4 waves/block x 64 ds_read_b128/slice = 1024 B/instr through a
// 128 B/cy path: ~12.3k LDS cy vs 8.2k VALU cy per CU slice-group; 72% =
// 8.2/12.3; barrier halving in R12 was a no-op, confirming). Fix: split the
// 4 accumulator lanes across an even/odd THREAD PAIR (each thread holds one
// v2f per output) so an 8x8 per-thread output region costs 128 acc VGPRs and
// reads 8 B/row (ds_read_b64) instead of 16: LDS bytes per pk-op halve.
// Per-lane rounding, k order, hadd shape (s01+s23)+b are bit-identical; the
// partner half-sum crosses via one __shfl_xor per output in the epilogue.
// New balance: LDS ~6.9k cy vs VALU 8.2k cy per CU slice-pair -> VALU-bound.
__global__ __launch_bounds__(256, 2) void snn_np_pair(
    const float* __restrict__ x,     // [B,T,K] f32
    const float* __restrict__ W,     // [H,K] f32
    const float* __restrict__ bias,  // [H] f32
    float* __restrict__ spikes,      // [B,T,H] f32 out
    float* __restrict__ memf)        // [B,H] f32 out
{
#pragma clang fp contract(off)       // numpy SSE path has no FMA: mul+add only
    __shared__ float smem[15296];    // 61184 B total
    float* const AB0 = smem;               // As0 @0, Bs0 @2304
    float* const AB1 = smem + BUFSZ;       // As1, Bs1
    float* const Ism = smem + ISMOFF;      // [64][129] — AB1 + pad (disjoint phases)
    float* const bsh = smem + BSHOFF;      // [128]

    const int tid = threadIdx.x;
    const int bb  = blockIdx.x;            // batch index
    const int h0  = blockIdx.y * BN;       // h tile origin

    const int sub = tid & 1;               // accumulator lane pair: {0,1} or {2,3}
    const int p   = tid >> 1;              // pair id 0..127
    const int px  = p & 15;                // h micro (8 cols, stride 16)
    const int pt  = p >> 4;                // t micro (8 rows, stride 8)

    const int srow = tid >> 3;             // staging row 0..31 (+32r)
    const int scol = (tid & 7) << 2;       // staging col 0,4,..,28

    const float* xb = x + (size_t)bb * T_ * KDIM;
    const float* Wb = W + (size_t)h0 * KDIM;

    if (tid < BN) bsh[tid] = bias[h0 + tid];

    float mem = 0.0f;                      // threads 0..127 carry h = h0+tid

    // ---- prologue: slice 0 -> AB0; slice 1 -> regs ----
    float4 pa0, pa1, pw0, pw1, pw2, pw3;
    pa0 = *(const float4*)&xb[(size_t)(srow)      * KDIM + scol];
    pa1 = *(const float4*)&xb[(size_t)(32 + srow) * KDIM + scol];
    pw0 = *(const float4*)&Wb[(size_t)(srow)      * KDIM + scol];
    pw1 = *(const float4*)&Wb[(size_t)(32 + srow) * KDIM + scol];
    pw2 = *(const float4*)&Wb[(size_t)(64 + srow) * KDIM + scol];
    pw3 = *(const float4*)&Wb[(size_t)(96 + srow) * KDIM + scol];
    *(float4*)&AB0[srow * LDA + scol]               = pa0;
    *(float4*)&AB0[(32 + srow) * LDA + scol]        = pa1;
    *(float4*)&AB0[BOFF + srow * LDA + scol]        = pw0;
    *(float4*)&AB0[BOFF + (32 + srow) * LDA + scol] = pw1;
    *(float4*)&AB0[BOFF + (64 + srow) * LDA + scol] = pw2;
    *(float4*)&AB0[BOFF + (96 + srow) * LDA + scol] = pw3;
    pa0 = *(const float4*)&xb[(size_t)(srow)      * KDIM + 32 + scol];
    pa1 = *(const float4*)&xb[(size_t)(32 + srow) * KDIM + 32 + scol];
    pw0 = *(const float4*)&Wb[(size_t)(srow)      * KDIM + 32 + scol];
    pw1 = *(const float4*)&Wb[(size_t)(32 + srow) * KDIM + 32 + scol];
    pw2 = *(const float4*)&Wb[(size_t)(64 + srow) * KDIM + 32 + scol];
    pw3 = *(const float4*)&Wb[(size_t)(96 + srow) * KDIM + 32 + scol];
    __syncthreads();                       // AB0 + bsh visible

    const int aoff = pt * LDA + 2 * sub;          // + j*(8*LDA) + qc
    const int boff = BOFF + px * LDA + 2 * sub;   // + i*(16*LDA) + qc

    for (int c = 0; c < T_ / BM; ++c) {
        // per-thread half-accumulators: lanes {2*sub, 2*sub+1} of 8x8 outputs
        v2f acc[8][8];
#pragma unroll
        for (int j = 0; j < 8; ++j)
#pragma unroll
            for (int i = 0; i < 8; ++i) acc[j][i] = (v2f)(0.0f);

        for (int s = 0; s < SPC; ++s) {
            const int g = c * SPC + s;
            float* const cb = (g & 1) ? AB1 : AB0;   // compute buffer (slice g)
            float* const nb = (g & 1) ? AB0 : AB1;   // commit target (slice g+1)

            // 1) commit regs (slice g+1) into nb — overlapped with compute
            if (g + 1 < NSL) {
                *(float4*)&nb[srow * LDA + scol]               = pa0;
                *(float4*)&nb[(32 + srow) * LDA + scol]        = pa1;
                *(float4*)&nb[BOFF + srow * LDA + scol]        = pw0;
                *(float4*)&nb[BOFF + (32 + srow) * LDA + scol] = pw1;
                *(float4*)&nb[BOFF + (64 + srow) * LDA + scol] = pw2;
                *(float4*)&nb[BOFF + (96 + srow) * LDA + scol] = pw3;
            }
            // 2) issue slice g+2 loads; a whole compute phase to land
            if (g + 2 < NSL) {
                const int gs  = g + 2;
                const int nt0 = (gs >> 5) * BM;
                const int nk  = (gs & 31) << 5;
                pa0 = *(const float4*)&xb[(size_t)(nt0 + srow)      * KDIM + nk + scol];
                pa1 = *(const float4*)&xb[(size_t)(nt0 + 32 + srow) * KDIM + nk + scol];
                pw0 = *(const float4*)&Wb[(size_t)(srow)      * KDIM + nk + scol];
                pw1 = *(const float4*)&Wb[(size_t)(32 + srow) * KDIM + nk + scol];
                pw2 = *(const float4*)&Wb[(size_t)(64 + srow) * KDIM + nk + scol];
                pw3 = *(const float4*)&Wb[(size_t)(96 + srow) * KDIM + nk + scol];
            }
            // 3) compute slice g: two numpy 16-k blocks ascending; q=3..0 —
            // per-lane acc += a*b, mul then add: byte-identical chain
#pragma unroll
            for (int kb = 0; kb < 2; ++kb) {
#pragma unroll
                for (int q = 3; q >= 0; --q) {
                    const int qc = (kb << 4) + (q << 2);
                    v2f av[8], bv[8];
#pragma unroll
                    for (int j = 0; j < 8; ++j)
                        av[j] = *(const v2f*)&cb[aoff + j * (8 * LDA) + qc];
#pragma unroll
                    for (int i = 0; i < 8; ++i)
                        bv[i] = *(const v2f*)&cb[boff + i * (16 * LDA) + qc];
#pragma unroll
                    for (int j = 0; j < 8; ++j)
#pragma unroll
                        for (int i = 0; i < 8; ++i) {
                            const v2f m = av[j] * bv[i];   // packed rounded muls
                            acc[j][i] = acc[j][i] + m;     // packed rounded adds
                        }
                }
            }
            __syncthreads();   // slice g reads done; slice g+1 commit visible
        }

        // epilogue: pair hadd (l0+l1)+(l2+l3), bias, write I chunk to Ism.
        // All slice-(c*32+31) reads of AB1 completed at the loop's last barrier;
        // the in-flight commit went to AB0 (chunk-final slices are odd).
#pragma unroll
        for (int j = 0; j < 8; ++j)
#pragma unroll
            for (int i = 0; i < 8; ++i) {
                const float sh = acc[j][i].x + acc[j][i].y;     // own half-sum
                const float so = __shfl_xor(sh, 1, 64);         // partner half
                if (sub == 0)
                    Ism[(pt + 8 * j) * ISMLD + (px + 16 * i)] =
                        (sh + so) + bsh[px + 16 * i];           // (s01+s23)+b
            }
        __syncthreads();

        // f32 LIF scan over this chunk; one thread per h.
        if (tid < BN) {
            const size_t srow0 = ((size_t)(bb * T_ + c * BM)) * HID_ + h0 + tid;
#pragma unroll 4
            for (int t = 0; t < BM; ++t) {
                const float It = Ism[t * ISMLD + tid];
                const float am = ALPHA_F * mem;   // rounded mul
                mem = am + It;                    // rounded add
                const bool fire = (mem >= 1.0f);
                spikes[srow0 + (size_t)t * HID_] = fire ? 1.0f : 0.0f;
                if (fire) mem = 0.0f;
            }
        }
        __syncthreads();   // scan's Ism reads done before next chunk's iter-0
                           // commit into AB1 (= Ism region)
    }

    if (tid < BN) memf[(size_t)bb * HID_ + h0 + tid] = mem;
}

extern "C" void kernel_launch(void* const* d_in, const int* in_sizes, int n_in,
                              void* d_out, int out_size, void* d_ws, size_t ws_size,
                              hipStream_t stream) {
    const float* x    = (const float*)d_in[0];   // [B,T,K] f32
    const float* W    = (const float*)d_in[1];   // [H,K] f32
    const float* bias = (const float*)d_in[2];   // [H] f32
    float* out    = (float*)d_out;
    float* spikes = out;                          // [B,T,H]
    float* memf   = out + (size_t)B_ * T_ * HID_; // [B,H]

    dim3 grid(B_, HID_ / BN);   // 64 x 8 = 512 blocks (exactly 2/CU)
    snn_np_pair<<<grid, dim3(256), 0, stream>>>(x, W, bias, spikes, memf);
}